// Round 11
// baseline (127.632 us; speedup 1.0000x reference)
//
#include <hip/hip_runtime.h>
#include <hip/hip_bf16.h>
#include <math.h>

#define NROWS 4096
#define DIN   1024
#define DOUT  256
#define NJB   64         // 64-col j-chunks for pmax/pmin partials
#define NPAIR 528        // 32*33/2 triangular 128x128 block pairs

using bfrag = __attribute__((ext_vector_type(8))) short;  // 8 bf16 (4 VGPRs)
using ffrag = __attribute__((ext_vector_type(4))) float;  // 4 fp32 acc

// Fragment-order layouts (mfma_f32_16x16x32_bf16; A and B share the per-lane
// map: elem[lane l][j] = M[tile*16 + (l&15)][ks*32 + (l>>4)*8 + j]):
//   Ws: frag f = (nt*32 + ks)*64 + l     nt<16 (W col-tiles), ks<32
//   hs: frag f = (t*8  + ks)*64 + l      t<256 (h row-tiles), ks<8  (K=256)

static __device__ __forceinline__ unsigned short f2bf(float f) {
    unsigned int u = __float_as_uint(f);
    u = (u + 0x7fffu + ((u >> 16) & 1u)) >> 16;
    return (unsigned short)u;
}
static __device__ __forceinline__ unsigned int pack2(float lo, float hi) {
    return (unsigned int)f2bf(lo) | ((unsigned int)f2bf(hi) << 16);
}
static __device__ __forceinline__ int packbf2(float lo, float hi) {
    float2 t; t.x = lo; t.y = hi;
    __hip_bfloat162 h = __float22bfloat162_rn(t);    // v_cvt_pk_bf16_f32 (RNE)
    union { __hip_bfloat162 h; int i; } u; u.h = h;
    return u.i;
}

// ---------------------------------------------------------------------------
// Kernel 0 (setup): Ws fragment conversion + sq/out zeroing. 128 blocks.
// ---------------------------------------------------------------------------
__global__ __launch_bounds__(256) void setup(const float* __restrict__ W,
                                             unsigned short* __restrict__ Ws,
                                             float* __restrict__ sq,
                                             float* __restrict__ out) {
    const int f  = blockIdx.x * 256 + threadIdx.x;   // 32768 Ws frags
    {
        const int l  = f & 63;
        const int ks = (f >> 6) & 31;
        const int nt = f >> 11;
        const int col = nt * 16 + (l & 15);
        const int k0  = ks * 32 + (l >> 4) * 8;
        float a[8];
#pragma unroll
        for (int j = 0; j < 8; ++j) a[j] = W[(size_t)(k0 + j) * DOUT + col];
        uint4 v;
        v.x = pack2(a[0], a[1]);
        v.y = pack2(a[2], a[3]);
        v.z = pack2(a[4], a[5]);
        v.w = pack2(a[6], a[7]);
        *(uint4*)&Ws[(size_t)f * 8] = v;
    }
    if (f < NROWS) sq[f] = 0.0f;
    if (f == 0) *out = 0.0f;
}

// ---------------------------------------------------------------------------
// Kernel 1: h = x@W + b with x-conversion FUSED (no xs buffer, no barriers).
// Block b: row-tile t = b>>2 shared by 4 waves (L1 reuse); wave w -> feature
// tile nt = (b&3)*4 + w. Per ks: coalesced fp32 x load (lane s: row s>>2,
// cols (s&3)*8, contiguous 32B) -> v_cvt_pk bf16 -> 4x ds_bpermute lane
// transpose (frag lane d sources lane (d&15)*4 + (d>>4)) -> MFMA.
// Epilogue: bias, row-sq atomicAdd, LDS micro-transpose -> hs frag store.
// ---------------------------------------------------------------------------
__global__ __launch_bounds__(256) void gemm1_fused(
    const float* __restrict__ x, const unsigned short* __restrict__ Ws,
    const float* __restrict__ b,
    unsigned short* __restrict__ hs, float* __restrict__ sq) {
    __shared__ __align__(16) short T[4][16][24];     // per-wave 16x16 tile (+pad)

    const int tid = threadIdx.x;
    const int w   = tid >> 6;
    const int l   = tid & 63;
    const int m16 = l & 15;
    const int q   = l >> 4;
    const int t   = blockIdx.x >> 2;             // x row-tile (0..255)
    const int nt  = (blockIdx.x & 3) * 4 + w;    // feature tile (0..15)

    const float* xr = x + (size_t)(t * 16 + (l >> 2)) * DIN + (l & 3) * 8;
    const int sidx = (((l & 15) * 4) + (l >> 4)) * 4;   // bpermute byte index
    const bfrag* B = (const bfrag*)Ws + ((size_t)nt * 32) * 64 + l;

    ffrag acc = {};
#pragma unroll
    for (int ks = 0; ks < 32; ++ks) {
        const float4 p0 = *(const float4*)(xr + ks * 32);
        const float4 p1 = *(const float4*)(xr + ks * 32 + 4);
        const int v0 = packbf2(p0.x, p0.y);
        const int v1 = packbf2(p0.z, p0.w);
        const int v2 = packbf2(p1.x, p1.y);
        const int v3 = packbf2(p1.z, p1.w);
        union { int i[4]; bfrag f; } u;
        u.i[0] = __builtin_amdgcn_ds_bpermute(sidx, v0);
        u.i[1] = __builtin_amdgcn_ds_bpermute(sidx, v1);
        u.i[2] = __builtin_amdgcn_ds_bpermute(sidx, v2);
        u.i[3] = __builtin_amdgcn_ds_bpermute(sidx, v3);
        acc = __builtin_amdgcn_mfma_f32_16x16x32_bf16(u.f, B[ks * 64], acc, 0, 0, 0);
    }

    const float bc = b[nt * 16 + m16];
    float hv[4];
#pragma unroll
    for (int reg = 0; reg < 4; ++reg) hv[reg] = acc[reg] + bc;

    // row-sq partial: row = t*16 + q*4 + reg; sum over this wave's 16 features
#pragma unroll
    for (int reg = 0; reg < 4; ++reg) {
        float p = hv[reg] * hv[reg];
#pragma unroll
        for (int mask = 1; mask < 16; mask <<= 1) p += __shfl_xor(p, mask);
        if (m16 == 0) atomicAdd(&sq[t * 16 + q * 4 + reg], p);
    }

    // transpose C-tile (row=q*4+reg, col=m16) to h-row-major via LDS
#pragma unroll
    for (int reg = 0; reg < 4; ++reg)
        T[w][q * 4 + reg][m16] = f2bf(hv[reg]);
    // same-wave LDS RAW: compiler inserts lgkmcnt wait; no __syncthreads needed

    const int ksH  = nt >> 1;         // hs k-slice (32 features)
    const int half = nt & 1;
    const int qp   = q - 2 * half;    // 0..1 for this wave's half of the frag
    if (qp >= 0 && qp < 2) {
        bfrag v = *(const bfrag*)&T[w][m16][qp * 8];
        ((bfrag*)hs)[((size_t)t * 8 + ksH) * 64 + l] = v;   // half-wave 512B store
    }
}

// ---------------------------------------------------------------------------
// Kernel 2: triangular register-direct Gram (g = g^T computed once per pair).
// ---------------------------------------------------------------------------
__global__ __launch_bounds__(256) void hardest_tri(
    const unsigned short* __restrict__ hs, const float* __restrict__ sq,
    const int* __restrict__ targets,
    float* __restrict__ pmax, float* __restrict__ pmin) {
    const int tid = threadIdx.x;
    const int w   = tid >> 6;
    const int wi  = w & 1, wj = w >> 1;
    const int l   = tid & 63;
    const int m16 = l & 15;
    const int q   = l >> 4;

    // decode triangular pair index k -> (bi <= bj)
    const int k = blockIdx.x;
    int bj = (int)((sqrtf(8.0f * (float)k + 1.0f) - 1.0f) * 0.5f);
    while ((bj + 1) * (bj + 2) / 2 <= k) ++bj;
    while (bj * (bj + 1) / 2 > k) --bj;
    const int bi = k - bj * (bj + 1) / 2;
    const bool diag = (bi == bj);

    const int iw = bi * 128 + wi * 64;
    const int jw = bj * 128 + wj * 64;
    const int tA = iw >> 4;
    const int tB = jw >> 4;

    ffrag acc[4][4] = {};                        // [mi][nj]

#pragma unroll
    for (int ks = 0; ks < 8; ++ks) {
        bfrag a[4], bb[4];
#pragma unroll
        for (int mi = 0; mi < 4; ++mi)
            a[mi] = *(const bfrag*)&hs[(((size_t)(tA + mi) * 8 + ks) * 64 + l) * 8];
#pragma unroll
        for (int nj = 0; nj < 4; ++nj)
            bb[nj] = *(const bfrag*)&hs[(((size_t)(tB + nj) * 8 + ks) * 64 + l) * 8];
#pragma unroll
        for (int mi = 0; mi < 4; ++mi)
#pragma unroll
            for (int nj = 0; nj < 4; ++nj)
                acc[mi][nj] = __builtin_amdgcn_mfma_f32_16x16x32_bf16(
                    a[mi], bb[nj], acc[mi][nj], 0, 0, 0);
    }

    // ---- fused epilogue, both directions ----
    int   tj[4];
    float svj[4];
#pragma unroll
    for (int nj = 0; nj < 4; ++nj) {
        const int col = jw + nj * 16 + m16;
        tj[nj]  = targets[col];
        svj[nj] = sq[col];
    }

    float cmx[4], cmn[4];
#pragma unroll
    for (int nj = 0; nj < 4; ++nj) { cmx[nj] = -INFINITY; cmn[nj] = INFINITY; }

    const int jblk = bj * 2 + wj;
#pragma unroll
    for (int mi = 0; mi < 4; ++mi)
#pragma unroll
        for (int reg = 0; reg < 4; ++reg) {
            const int row = iw + mi * 16 + q * 4 + reg;
            const int ti  = targets[row];
            const float si = sq[row];
            float mx = -INFINITY, mn = INFINITY;
#pragma unroll
            for (int nj = 0; nj < 4; ++nj) {
                const float g    = acc[mi][nj][reg];
                const float vrow = fmaf(-2.0f, g, svj[nj]);
                const float vcol = fmaf(-2.0f, g, si);
                if (tj[nj] == ti) {
                    mx = fmaxf(mx, vrow);
                    cmx[nj] = fmaxf(cmx[nj], vcol);
                } else {
                    mn = fminf(mn, vrow);
                    cmn[nj] = fminf(cmn[nj], vcol);
                }
            }
            // row-side: reduce over the 16 m16-lanes
#pragma unroll
            for (int mask = 1; mask < 16; mask <<= 1) {
                mx = fmaxf(mx, __shfl_xor(mx, mask));
                mn = fminf(mn, __shfl_xor(mn, mask));
            }
            if (m16 == 0) {
                pmax[(size_t)jblk * NROWS + row] = mx;
                pmin[(size_t)jblk * NROWS + row] = mn;
            }
        }

    // col-side: reduce over the q bits (lanes 16,32 apart), skip on diagonal
    if (!diag) {
        const int iblk = bi * 2 + wi;
#pragma unroll
        for (int nj = 0; nj < 4; ++nj) {
            float mx = cmx[nj], mn = cmn[nj];
            mx = fmaxf(mx, __shfl_xor(mx, 16));
            mn = fminf(mn, __shfl_xor(mn, 16));
            mx = fmaxf(mx, __shfl_xor(mx, 32));
            mn = fminf(mn, __shfl_xor(mn, 32));
            if (q == 0) {
                const int col = jw + nj * 16 + m16;
                pmax[(size_t)iblk * NROWS + col] = mx;
                pmin[(size_t)iblk * NROWS + col] = mn;
            }
        }
    }
}

// ---------------------------------------------------------------------------
// Kernel 3: combine chunk partials, per-row loss, sum -> out[0]
// ---------------------------------------------------------------------------
__global__ __launch_bounds__(256) void finalize(const float* __restrict__ sq,
                                                const float* __restrict__ pmax,
                                                const float* __restrict__ pmin,
                                                float* __restrict__ out) {
    __shared__ float wsum[4];
    const int i = blockIdx.x * 256 + threadIdx.x;
    float mp = -INFINITY, mn = INFINITY;
#pragma unroll
    for (int c = 0; c < NJB; ++c) {
        mp = fmaxf(mp, pmax[c * NROWS + i]);
        mn = fminf(mn, pmin[c * NROWS + i]);
    }
    const float si = sq[i];
    const float hp = sqrtf(fmaxf(si + mp, 0.0f));
    const float hn = sqrtf(fmaxf(si + mn, 0.0f));
    const float d  = hp - hn;
    float li = fmaxf(d, 0.0f) + log1pf(expf(-fabsf(d)));  // stable log1p(exp(d))
#pragma unroll
    for (int off = 32; off; off >>= 1) li += __shfl_down(li, off);
    const int lane = threadIdx.x & 63, wv = threadIdx.x >> 6;
    if (lane == 0) wsum[wv] = li;
    __syncthreads();
    if (threadIdx.x == 0)
        atomicAdd(out, wsum[0] + wsum[1] + wsum[2] + wsum[3]);
}

// ---------------------------------------------------------------------------
extern "C" void kernel_launch(void* const* d_in, const int* in_sizes, int n_in,
                              void* d_out, int out_size, void* d_ws, size_t ws_size,
                              hipStream_t stream) {
    const float* x       = (const float*)d_in[0];
    const float* W       = (const float*)d_in[1];
    const float* b       = (const float*)d_in[2];
    const int*   targets = (const int*)d_in[3];
    float* out = (float*)d_out;

    unsigned short* Ws   = (unsigned short*)d_ws;               // 256*1024 bf16 (frag order)
    unsigned short* hs   = Ws + DOUT * DIN;                     // 4096*256 bf16 (frag order)
    float*          sq   = (float*)(hs + NROWS * DOUT);         // 4096
    float*          pmax = sq + NROWS;                          // [64][4096]
    float*          pmin = pmax + NJB * NROWS;                  // [64][4096]

    setup<<<16 * 32 * 64 / 256, 256, 0, stream>>>(W, Ws, sq, out);
    gemm1_fused<<<NROWS / 16 * 4, 256, 0, stream>>>(x, Ws, b, hs, sq);
    hardest_tri<<<NPAIR, 256, 0, stream>>>(hs, sq, targets, pmax, pmin);
    finalize<<<NROWS / 256, 256, 0, stream>>>(sq, pmax, pmin, out);
}

// Round 12
// 120.690 us; speedup vs baseline: 1.0575x; 1.0575x over previous
//
#include <hip/hip_runtime.h>
#include <math.h>

#define NROWS 4096
#define DIN   1024
#define DOUT  256
#define NJB   64         // 64-col j-chunks for pmax/pmin partials
#define NPAIR 528        // 32*33/2 triangular 128x128 block pairs

using bfrag = __attribute__((ext_vector_type(8))) short;  // 8 bf16 (4 VGPRs)
using ffrag = __attribute__((ext_vector_type(4))) float;  // 4 fp32 acc

// Fragment-order layouts (mfma_f32_16x16x32_bf16; A and B share the per-lane
// map: elem[lane l][j] = M[tile*16 + (l&15)][ks*32 + (l>>4)*8 + j]):
//   xs: frag f = (t*32 + ks)*64 + l      t<256 (x row-tiles), ks<32 (K=1024)
//   Ws: frag f = (nt*32 + ks)*64 + l     nt<16 (W col-tiles), ks<32
//   hs: frag f = (t*8  + ks)*64 + l      t<256 (h row-tiles), ks<8  (K=256)

static __device__ __forceinline__ unsigned short f2bf(float f) {
    unsigned int u = __float_as_uint(f);
    u = (u + 0x7fffu + ((u >> 16) & 1u)) >> 16;
    return (unsigned short)u;
}
static __device__ __forceinline__ unsigned int pack2(float lo, float hi) {
    return (unsigned int)f2bf(lo) | ((unsigned int)f2bf(hi) << 16);
}

// ---------------------------------------------------------------------------
// Kernel 0 (setup): xs via coalesced load + LDS transpose; Ws gather (first
// 128 blocks); sq/out zeroing. Grid = 1024 blocks (t 0..255 x kg 0..3).
// Load: 16 rows x 256 cols fp32, fully coalesced. LDS tile stride 264 shorts
// (528B = 33x16B: 16B-aligned rows, frag reads 2-way conflict only).
// Emit: 512 frags (8 ks x 64 lanes), contiguous 1KB per 64 threads.
// ---------------------------------------------------------------------------
__global__ __launch_bounds__(256) void setup(const float* __restrict__ x,
                                             const float* __restrict__ W,
                                             unsigned short* __restrict__ xs,
                                             unsigned short* __restrict__ Ws,
                                             float* __restrict__ sq,
                                             float* __restrict__ out) {
    __shared__ short Lt[16][264];
    const int tid = threadIdx.x;
    const int t   = blockIdx.x >> 2;     // x row-tile
    const int kg  = blockIdx.x & 3;      // 8-ks group (256 cols)

    // load + convert: thread (r = tid>>4, c4 = tid&15), 4 float4 sweeps
    const int r  = tid >> 4;
    const int c4 = tid & 15;
    const float* xr = x + (size_t)(t * 16 + r) * DIN + kg * 256;
#pragma unroll
    for (int i = 0; i < 4; ++i) {
        const int col = (c4 + 16 * i) * 4;
        const float4 v = *(const float4*)(xr + col);
        ushort4 h;
        h.x = f2bf(v.x);
        h.y = f2bf(v.y);
        h.z = f2bf(v.z);
        h.w = f2bf(v.w);
        *(ushort4*)&Lt[r][col] = h;
    }
    __syncthreads();

    // emit fragments: fid = o*256+tid -> ksl = fid>>6 (0..7), l = fid&63
#pragma unroll
    for (int o = 0; o < 2; ++o) {
        const int fid = o * 256 + tid;
        const int ksl = fid >> 6;
        const int l   = fid & 63;
        bfrag v = *(const bfrag*)&Lt[l & 15][ksl * 32 + (l >> 4) * 8];
        const size_t f = ((size_t)t * 32 + kg * 8 + ksl) * 64 + l;
        *(bfrag*)&xs[f * 8] = v;
    }

    // Ws gather (blocks 0..127), sq/out zero
    const int f = blockIdx.x * 256 + tid;
    if (f < 32768) {
        const int l  = f & 63;
        const int ks = (f >> 6) & 31;
        const int nt = f >> 11;
        const int col = nt * 16 + (l & 15);
        const int k0  = ks * 32 + (l >> 4) * 8;
        float a[8];
#pragma unroll
        for (int j = 0; j < 8; ++j) a[j] = W[(size_t)(k0 + j) * DOUT + col];
        uint4 v;
        v.x = pack2(a[0], a[1]);
        v.y = pack2(a[2], a[3]);
        v.z = pack2(a[4], a[5]);
        v.w = pack2(a[6], a[7]);
        *(uint4*)&Ws[(size_t)f * 8] = v;
    }
    if (f < NROWS) sq[f] = 0.0f;
    if (f == 0) *out = 0.0f;
}

// ---------------------------------------------------------------------------
// Kernel 1: h = x@W + b, register-direct MFMA, NO barriers in the K-loop.
// One 16x16 output tile per wave: 32 ks of (2 coalesced frag loads + 1 MFMA).
// ---------------------------------------------------------------------------
__global__ __launch_bounds__(256) void gemm1_reg(
    const unsigned short* __restrict__ xs, const unsigned short* __restrict__ Ws,
    const float* __restrict__ b,
    unsigned short* __restrict__ hs, float* __restrict__ sq) {
    __shared__ __align__(16) short T[4][16][24];     // per-wave 16x16 tile (+pad)

    const int tid = threadIdx.x;
    const int w   = tid >> 6;
    const int l   = tid & 63;
    const int m16 = l & 15;
    const int q   = l >> 4;
    const int gw  = blockIdx.x * 4 + w;
    const int t   = gw >> 4;     // x row-tile (0..255)
    const int nt  = gw & 15;     // feature tile (0..15)

    const bfrag* A = (const bfrag*)xs + ((size_t)t * 32) * 64 + l;
    const bfrag* B = (const bfrag*)Ws + ((size_t)nt * 32) * 64 + l;

    ffrag acc = {};
#pragma unroll
    for (int ks = 0; ks < 32; ++ks)
        acc = __builtin_amdgcn_mfma_f32_16x16x32_bf16(A[ks * 64], B[ks * 64], acc, 0, 0, 0);

    const float bc = b[nt * 16 + m16];
    float hv[4];
#pragma unroll
    for (int reg = 0; reg < 4; ++reg) hv[reg] = acc[reg] + bc;

    // row-sq partial: row = t*16 + q*4 + reg; sum over this wave's 16 features
#pragma unroll
    for (int reg = 0; reg < 4; ++reg) {
        float p = hv[reg] * hv[reg];
#pragma unroll
        for (int mask = 1; mask < 16; mask <<= 1) p += __shfl_xor(p, mask);
        if (m16 == 0) atomicAdd(&sq[t * 16 + q * 4 + reg], p);
    }

    // transpose C-tile (row=q*4+reg, col=m16) to h-row-major via LDS
#pragma unroll
    for (int reg = 0; reg < 4; ++reg)
        T[w][q * 4 + reg][m16] = f2bf(hv[reg]);
    // same-wave LDS RAW: compiler inserts lgkmcnt wait; no __syncthreads needed

    const int ksH  = nt >> 1;         // hs k-slice (32 features)
    const int half = nt & 1;
    const int qp   = q - 2 * half;    // 0..1 for this wave's half of the frag
    if (qp >= 0 && qp < 2) {
        bfrag v = *(const bfrag*)&T[w][m16][qp * 8];
        ((bfrag*)hs)[((size_t)t * 8 + ksH) * 64 + l] = v;   // half-wave 512B store
    }
}

// ---------------------------------------------------------------------------
// Kernel 2: triangular register-direct Gram (g = g^T computed once per pair).
// ---------------------------------------------------------------------------
__global__ __launch_bounds__(256) void hardest_tri(
    const unsigned short* __restrict__ hs, const float* __restrict__ sq,
    const int* __restrict__ targets,
    float* __restrict__ pmax, float* __restrict__ pmin) {
    const int tid = threadIdx.x;
    const int w   = tid >> 6;
    const int wi  = w & 1, wj = w >> 1;
    const int l   = tid & 63;
    const int m16 = l & 15;
    const int q   = l >> 4;

    // decode triangular pair index k -> (bi <= bj)
    const int k = blockIdx.x;
    int bj = (int)((sqrtf(8.0f * (float)k + 1.0f) - 1.0f) * 0.5f);
    while ((bj + 1) * (bj + 2) / 2 <= k) ++bj;
    while (bj * (bj + 1) / 2 > k) --bj;
    const int bi = k - bj * (bj + 1) / 2;
    const bool diag = (bi == bj);

    const int iw = bi * 128 + wi * 64;
    const int jw = bj * 128 + wj * 64;
    const int tA = iw >> 4;
    const int tB = jw >> 4;

    ffrag acc[4][4] = {};                        // [mi][nj]

#pragma unroll
    for (int ks = 0; ks < 8; ++ks) {
        bfrag a[4], bb[4];
#pragma unroll
        for (int mi = 0; mi < 4; ++mi)
            a[mi] = *(const bfrag*)&hs[(((size_t)(tA + mi) * 8 + ks) * 64 + l) * 8];
#pragma unroll
        for (int nj = 0; nj < 4; ++nj)
            bb[nj] = *(const bfrag*)&hs[(((size_t)(tB + nj) * 8 + ks) * 64 + l) * 8];
#pragma unroll
        for (int mi = 0; mi < 4; ++mi)
#pragma unroll
            for (int nj = 0; nj < 4; ++nj)
                acc[mi][nj] = __builtin_amdgcn_mfma_f32_16x16x32_bf16(
                    a[mi], bb[nj], acc[mi][nj], 0, 0, 0);
    }

    // ---- fused epilogue, both directions ----
    int   tj[4];
    float svj[4];
#pragma unroll
    for (int nj = 0; nj < 4; ++nj) {
        const int col = jw + nj * 16 + m16;
        tj[nj]  = targets[col];
        svj[nj] = sq[col];
    }

    float cmx[4], cmn[4];
#pragma unroll
    for (int nj = 0; nj < 4; ++nj) { cmx[nj] = -INFINITY; cmn[nj] = INFINITY; }

    const int jblk = bj * 2 + wj;
#pragma unroll
    for (int mi = 0; mi < 4; ++mi)
#pragma unroll
        for (int reg = 0; reg < 4; ++reg) {
            const int row = iw + mi * 16 + q * 4 + reg;
            const int ti  = targets[row];
            const float si = sq[row];
            float mx = -INFINITY, mn = INFINITY;
#pragma unroll
            for (int nj = 0; nj < 4; ++nj) {
                const float g    = acc[mi][nj][reg];
                const float vrow = fmaf(-2.0f, g, svj[nj]);
                const float vcol = fmaf(-2.0f, g, si);
                if (tj[nj] == ti) {
                    mx = fmaxf(mx, vrow);
                    cmx[nj] = fmaxf(cmx[nj], vcol);
                } else {
                    mn = fminf(mn, vrow);
                    cmn[nj] = fminf(cmn[nj], vcol);
                }
            }
            // row-side: reduce over the 16 m16-lanes
#pragma unroll
            for (int mask = 1; mask < 16; mask <<= 1) {
                mx = fmaxf(mx, __shfl_xor(mx, mask));
                mn = fminf(mn, __shfl_xor(mn, mask));
            }
            if (m16 == 0) {
                pmax[(size_t)jblk * NROWS + row] = mx;
                pmin[(size_t)jblk * NROWS + row] = mn;
            }
        }

    // col-side: reduce over the q bits (lanes 16,32 apart), skip on diagonal
    if (!diag) {
        const int iblk = bi * 2 + wi;
#pragma unroll
        for (int nj = 0; nj < 4; ++nj) {
            float mx = cmx[nj], mn = cmn[nj];
            mx = fmaxf(mx, __shfl_xor(mx, 16));
            mn = fminf(mn, __shfl_xor(mn, 16));
            mx = fmaxf(mx, __shfl_xor(mx, 32));
            mn = fminf(mn, __shfl_xor(mn, 32));
            if (q == 0) {
                const int col = jw + nj * 16 + m16;
                pmax[(size_t)iblk * NROWS + col] = mx;
                pmin[(size_t)iblk * NROWS + col] = mn;
            }
        }
    }
}

// ---------------------------------------------------------------------------
// Kernel 3: combine chunk partials, per-row loss, sum -> out[0]
// ---------------------------------------------------------------------------
__global__ __launch_bounds__(256) void finalize(const float* __restrict__ sq,
                                                const float* __restrict__ pmax,
                                                const float* __restrict__ pmin,
                                                float* __restrict__ out) {
    __shared__ float wsum[4];
    const int i = blockIdx.x * 256 + threadIdx.x;
    float mp = -INFINITY, mn = INFINITY;
#pragma unroll
    for (int c = 0; c < NJB; ++c) {
        mp = fmaxf(mp, pmax[c * NROWS + i]);
        mn = fminf(mn, pmin[c * NROWS + i]);
    }
    const float si = sq[i];
    const float hp = sqrtf(fmaxf(si + mp, 0.0f));
    const float hn = sqrtf(fmaxf(si + mn, 0.0f));
    const float d  = hp - hn;
    float li = fmaxf(d, 0.0f) + log1pf(expf(-fabsf(d)));  // stable log1p(exp(d))
#pragma unroll
    for (int off = 32; off; off >>= 1) li += __shfl_down(li, off);
    const int lane = threadIdx.x & 63, wv = threadIdx.x >> 6;
    if (lane == 0) wsum[wv] = li;
    __syncthreads();
    if (threadIdx.x == 0)
        atomicAdd(out, wsum[0] + wsum[1] + wsum[2] + wsum[3]);
}

// ---------------------------------------------------------------------------
extern "C" void kernel_launch(void* const* d_in, const int* in_sizes, int n_in,
                              void* d_out, int out_size, void* d_ws, size_t ws_size,
                              hipStream_t stream) {
    const float* x       = (const float*)d_in[0];
    const float* W       = (const float*)d_in[1];
    const float* b       = (const float*)d_in[2];
    const int*   targets = (const int*)d_in[3];
    float* out = (float*)d_out;

    unsigned short* Ws   = (unsigned short*)d_ws;               // 256*1024 bf16 (frag order)
    unsigned short* xs   = Ws + DOUT * DIN;                     // 4096*1024 bf16 (frag order)
    unsigned short* hs   = xs + (size_t)NROWS * DIN;            // 4096*256 bf16 (frag order)
    float*          sq   = (float*)(hs + NROWS * DOUT);         // 4096
    float*          pmax = sq + NROWS;                          // [64][4096]
    float*          pmin = pmax + NJB * NROWS;                  // [64][4096]

    setup<<<NROWS / 16 * 4, 256, 0, stream>>>(x, W, xs, Ws, sq, out);
    gemm1_reg<<<NROWS / 16 * 16 / 4, 256, 0, stream>>>(xs, Ws, b, hs, sq);
    hardest_tri<<<NPAIR, 256, 0, stream>>>(hs, sq, targets, pmax, pmin);
    finalize<<<NROWS / 256, 256, 0, stream>>>(sq, pmax, pmin, out);
}

// Round 13
// 116.859 us; speedup vs baseline: 1.0922x; 1.0328x over previous
//
#include <hip/hip_runtime.h>
#include <math.h>

#define NROWS 4096
#define DIN   1024
#define DOUT  256
#define NJB   64         // 64-col j-chunks for pmax/pmin partials
#define NPAIR 528        // 32*33/2 triangular 128x128 block pairs

using bfrag = __attribute__((ext_vector_type(8))) short;  // 8 bf16 (4 VGPRs)
using ffrag = __attribute__((ext_vector_type(4))) float;  // 4 fp32 acc

// Fragment-order layouts (mfma_f32_16x16x32_bf16; A and B share the per-lane
// map: elem[lane l][j] = M[tile*16 + (l&15)][ks*32 + (l>>4)*8 + j]):
//   Ws: frag f = (nt*32 + ks)*64 + l     nt<16 (W col-tiles), ks<32
//   hs: frag f = (t*8  + ks)*64 + l      t<256 (h row-tiles), ks<8  (K=256)

static __device__ __forceinline__ unsigned short f2bf(float f) {
    unsigned int u = __float_as_uint(f);
    u = (u + 0x7fffu + ((u >> 16) & 1u)) >> 16;
    return (unsigned short)u;
}
static __device__ __forceinline__ unsigned int pack2(float lo, float hi) {
    return (unsigned int)f2bf(lo) | ((unsigned int)f2bf(hi) << 16);
}

// ---------------------------------------------------------------------------
// Kernel 0 (setup): Ws fragment gather + sq/out zeroing. 128 blocks.
// ---------------------------------------------------------------------------
__global__ __launch_bounds__(256) void setup(const float* __restrict__ W,
                                             unsigned short* __restrict__ Ws,
                                             float* __restrict__ sq,
                                             float* __restrict__ out) {
    const int f = blockIdx.x * 256 + threadIdx.x;    // 32768 Ws frags
    {
        const int l  = f & 63;
        const int ks = (f >> 6) & 31;
        const int nt = f >> 11;
        const int col = nt * 16 + (l & 15);
        const int k0  = ks * 32 + (l >> 4) * 8;
        float a[8];
#pragma unroll
        for (int j = 0; j < 8; ++j) a[j] = W[(size_t)(k0 + j) * DOUT + col];
        uint4 v;
        v.x = pack2(a[0], a[1]);
        v.y = pack2(a[2], a[3]);
        v.z = pack2(a[4], a[5]);
        v.w = pack2(a[6], a[7]);
        *(uint4*)&Ws[(size_t)f * 8] = v;
    }
    if (f < NROWS) sq[f] = 0.0f;
    if (f == 0) *out = 0.0f;
}

// ---------------------------------------------------------------------------
// Kernel 1: h = x@W + b with x staged to frag-order LDS (NO xs buffer).
// Block = (t, h): row-tile t (16 rows), nt-half h (8 feature tiles).
// Stage: 16x1024 fp32 coalesced -> bf16 frag-order LDS (528-short ks stride:
// writer <=2-way bank conflict (free), reader 1KB/wave contiguous). 1 barrier.
// Wave w: nt pair (h*8 + w*2 + {0,1}): 32 ks x (1 LDS A-frag + 2 B-frags + 2
// MFMA). Epilogue: bias, row-sq atomicAdd, per-wave LDS transpose -> hs frag
// (the wave's 32 features = exactly hs k-slice h*4+w), full-wave 1KB store.
// ---------------------------------------------------------------------------
__global__ __launch_bounds__(256) void gemm1_direct(
    const float* __restrict__ x, const unsigned short* __restrict__ Ws,
    const float* __restrict__ b,
    unsigned short* __restrict__ hs, float* __restrict__ sq) {
    __shared__ __align__(16) short Axs[32 * 528];    // 33792 B frag-order A strip
    __shared__ __align__(16) short T[4][16][36];     // per-wave C transpose

    const int tid = threadIdx.x;
    const int w   = tid >> 6;
    const int l   = tid & 63;
    const int m16 = l & 15;
    const int q   = l >> 4;
    const int t   = blockIdx.x >> 1;     // x row-tile (0..255)
    const int h   = blockIdx.x & 1;      // nt half (0..1)

    // ---- stage x strip ----
    const int r  = tid >> 4;             // row 0..15
    const int cc = tid & 15;
    const float* xrow = x + (size_t)(t * 16 + r) * DIN;
#pragma unroll
    for (int s = 0; s < 8; ++s) {
        const int c = s * 128 + cc * 8;
        const float4 p0 = *(const float4*)(xrow + c);
        const float4 p1 = *(const float4*)(xrow + c + 4);
        uint4 v;
        v.x = pack2(p0.x, p0.y);
        v.y = pack2(p0.z, p0.w);
        v.z = pack2(p1.x, p1.y);
        v.w = pack2(p1.z, p1.w);
        const int ks = c >> 5;
        const int lw = ((c >> 3) & 3) * 16 + r;
        *(uint4*)&Axs[ks * 528 + lw * 8] = v;
    }
    __syncthreads();

    // ---- K-loop ----
    const int nt0 = h * 8 + w * 2;
    const bfrag* B0 = (const bfrag*)Ws + ((size_t)nt0 * 32) * 64 + l;
    const bfrag* B1 = (const bfrag*)Ws + ((size_t)(nt0 + 1) * 32) * 64 + l;

    ffrag acc0 = {}, acc1 = {};
#pragma unroll
    for (int ks = 0; ks < 32; ++ks) {
        const bfrag a = *(const bfrag*)&Axs[ks * 528 + l * 8];
        acc0 = __builtin_amdgcn_mfma_f32_16x16x32_bf16(a, B0[ks * 64], acc0, 0, 0, 0);
        acc1 = __builtin_amdgcn_mfma_f32_16x16x32_bf16(a, B1[ks * 64], acc1, 0, 0, 0);
    }

    // ---- epilogue ----
    const float bc0 = b[nt0 * 16 + m16];
    const float bc1 = b[(nt0 + 1) * 16 + m16];
    float hv0[4], hv1[4];
#pragma unroll
    for (int reg = 0; reg < 4; ++reg) {
        hv0[reg] = acc0[reg] + bc0;
        hv1[reg] = acc1[reg] + bc1;
    }

    // row-sq partial over this wave's 32 features
#pragma unroll
    for (int reg = 0; reg < 4; ++reg) {
        float p = hv0[reg] * hv0[reg] + hv1[reg] * hv1[reg];
#pragma unroll
        for (int mask = 1; mask < 16; mask <<= 1) p += __shfl_xor(p, mask);
        if (m16 == 0) atomicAdd(&sq[t * 16 + q * 4 + reg], p);
    }

    // per-wave transpose (rows q*4+reg, cols u*16+m16) -> hs frag order
#pragma unroll
    for (int reg = 0; reg < 4; ++reg) {
        T[w][q * 4 + reg][m16]      = f2bf(hv0[reg]);
        T[w][q * 4 + reg][16 + m16] = f2bf(hv1[reg]);
    }
    // same-wave LDS RAW: in-order LDS ops + lgkmcnt wait; no barrier needed
    const int ksH = h * 4 + w;           // hs k-slice of this wave's 32 features
    bfrag v = *(const bfrag*)&T[w][m16][q * 8];
    ((bfrag*)hs)[((size_t)t * 8 + ksH) * 64 + l] = v;   // full-wave 1KB store
}

// ---------------------------------------------------------------------------
// Kernel 2: triangular register-direct Gram (g = g^T computed once per pair).
// ---------------------------------------------------------------------------
__global__ __launch_bounds__(256) void hardest_tri(
    const unsigned short* __restrict__ hs, const float* __restrict__ sq,
    const int* __restrict__ targets,
    float* __restrict__ pmax, float* __restrict__ pmin) {
    const int tid = threadIdx.x;
    const int w   = tid >> 6;
    const int wi  = w & 1, wj = w >> 1;
    const int l   = tid & 63;
    const int m16 = l & 15;
    const int q   = l >> 4;

    // decode triangular pair index k -> (bi <= bj)
    const int k = blockIdx.x;
    int bj = (int)((sqrtf(8.0f * (float)k + 1.0f) - 1.0f) * 0.5f);
    while ((bj + 1) * (bj + 2) / 2 <= k) ++bj;
    while (bj * (bj + 1) / 2 > k) --bj;
    const int bi = k - bj * (bj + 1) / 2;
    const bool diag = (bi == bj);

    const int iw = bi * 128 + wi * 64;
    const int jw = bj * 128 + wj * 64;
    const int tA = iw >> 4;
    const int tB = jw >> 4;

    ffrag acc[4][4] = {};                        // [mi][nj]

#pragma unroll
    for (int ks = 0; ks < 8; ++ks) {
        bfrag a[4], bb[4];
#pragma unroll
        for (int mi = 0; mi < 4; ++mi)
            a[mi] = *(const bfrag*)&hs[(((size_t)(tA + mi) * 8 + ks) * 64 + l) * 8];
#pragma unroll
        for (int nj = 0; nj < 4; ++nj)
            bb[nj] = *(const bfrag*)&hs[(((size_t)(tB + nj) * 8 + ks) * 64 + l) * 8];
#pragma unroll
        for (int mi = 0; mi < 4; ++mi)
#pragma unroll
            for (int nj = 0; nj < 4; ++nj)
                acc[mi][nj] = __builtin_amdgcn_mfma_f32_16x16x32_bf16(
                    a[mi], bb[nj], acc[mi][nj], 0, 0, 0);
    }

    // ---- fused epilogue, both directions ----
    int   tj[4];
    float svj[4];
#pragma unroll
    for (int nj = 0; nj < 4; ++nj) {
        const int col = jw + nj * 16 + m16;
        tj[nj]  = targets[col];
        svj[nj] = sq[col];
    }

    float cmx[4], cmn[4];
#pragma unroll
    for (int nj = 0; nj < 4; ++nj) { cmx[nj] = -INFINITY; cmn[nj] = INFINITY; }

    const int jblk = bj * 2 + wj;
#pragma unroll
    for (int mi = 0; mi < 4; ++mi)
#pragma unroll
        for (int reg = 0; reg < 4; ++reg) {
            const int row = iw + mi * 16 + q * 4 + reg;
            const int ti  = targets[row];
            const float si = sq[row];
            float mx = -INFINITY, mn = INFINITY;
#pragma unroll
            for (int nj = 0; nj < 4; ++nj) {
                const float g    = acc[mi][nj][reg];
                const float vrow = fmaf(-2.0f, g, svj[nj]);
                const float vcol = fmaf(-2.0f, g, si);
                if (tj[nj] == ti) {
                    mx = fmaxf(mx, vrow);
                    cmx[nj] = fmaxf(cmx[nj], vcol);
                } else {
                    mn = fminf(mn, vrow);
                    cmn[nj] = fminf(cmn[nj], vcol);
                }
            }
            // row-side: reduce over the 16 m16-lanes
#pragma unroll
            for (int mask = 1; mask < 16; mask <<= 1) {
                mx = fmaxf(mx, __shfl_xor(mx, mask));
                mn = fminf(mn, __shfl_xor(mn, mask));
            }
            if (m16 == 0) {
                pmax[(size_t)jblk * NROWS + row] = mx;
                pmin[(size_t)jblk * NROWS + row] = mn;
            }
        }

    // col-side: reduce over the q bits (lanes 16,32 apart), skip on diagonal
    if (!diag) {
        const int iblk = bi * 2 + wi;
#pragma unroll
        for (int nj = 0; nj < 4; ++nj) {
            float mx = cmx[nj], mn = cmn[nj];
            mx = fmaxf(mx, __shfl_xor(mx, 16));
            mn = fminf(mn, __shfl_xor(mn, 16));
            mx = fmaxf(mx, __shfl_xor(mx, 32));
            mn = fminf(mn, __shfl_xor(mn, 32));
            if (q == 0) {
                const int col = jw + nj * 16 + m16;
                pmax[(size_t)iblk * NROWS + col] = mx;
                pmin[(size_t)iblk * NROWS + col] = mn;
            }
        }
    }
}

// ---------------------------------------------------------------------------
// Kernel 3: combine chunk partials, per-row loss, sum -> out[0]
// ---------------------------------------------------------------------------
__global__ __launch_bounds__(256) void finalize(const float* __restrict__ sq,
                                                const float* __restrict__ pmax,
                                                const float* __restrict__ pmin,
                                                float* __restrict__ out) {
    __shared__ float wsum[4];
    const int i = blockIdx.x * 256 + threadIdx.x;
    float mp = -INFINITY, mn = INFINITY;
#pragma unroll
    for (int c = 0; c < NJB; ++c) {
        mp = fmaxf(mp, pmax[c * NROWS + i]);
        mn = fminf(mn, pmin[c * NROWS + i]);
    }
    const float si = sq[i];
    const float hp = sqrtf(fmaxf(si + mp, 0.0f));
    const float hn = sqrtf(fmaxf(si + mn, 0.0f));
    const float d  = hp - hn;
    float li = fmaxf(d, 0.0f) + log1pf(expf(-fabsf(d)));  // stable log1p(exp(d))
#pragma unroll
    for (int off = 32; off; off >>= 1) li += __shfl_down(li, off);
    const int lane = threadIdx.x & 63, wv = threadIdx.x >> 6;
    if (lane == 0) wsum[wv] = li;
    __syncthreads();
    if (threadIdx.x == 0)
        atomicAdd(out, wsum[0] + wsum[1] + wsum[2] + wsum[3]);
}

// ---------------------------------------------------------------------------
extern "C" void kernel_launch(void* const* d_in, const int* in_sizes, int n_in,
                              void* d_out, int out_size, void* d_ws, size_t ws_size,
                              hipStream_t stream) {
    const float* x       = (const float*)d_in[0];
    const float* W       = (const float*)d_in[1];
    const float* b       = (const float*)d_in[2];
    const int*   targets = (const int*)d_in[3];
    float* out = (float*)d_out;

    unsigned short* Ws   = (unsigned short*)d_ws;               // 256*1024 bf16 (frag order)
    unsigned short* hs   = Ws + DOUT * DIN;                     // 4096*256 bf16 (frag order)
    float*          sq   = (float*)(hs + NROWS * DOUT);         // 4096
    float*          pmax = sq + NROWS;                          // [64][4096]
    float*          pmin = pmax + NJB * NROWS;                  // [64][4096]

    setup<<<16 * 32 * 64 / 256, 256, 0, stream>>>(W, Ws, sq, out);
    gemm1_direct<<<NROWS / 16 * 2, 256, 0, stream>>>(x, Ws, b, hs, sq);
    hardest_tri<<<NPAIR, 256, 0, stream>>>(hs, sq, targets, pmax, pmin);
    finalize<<<NROWS / 256, 256, 0, stream>>>(sq, pmax, pmin, out);
}

// Round 14
// 99.029 us; speedup vs baseline: 1.2888x; 1.1800x over previous
//
#include <hip/hip_runtime.h>
#include <math.h>

#define NROWS 4096
#define DIN   1024
#define DOUT  256
#define NPAIR 528        // 32*33/2 triangular 128x128 block pairs

using bfrag = __attribute__((ext_vector_type(8))) short;  // 8 bf16 (4 VGPRs)
using ffrag = __attribute__((ext_vector_type(4))) float;  // 4 fp32 acc

// Fragment-order layouts (mfma_f32_16x16x32_bf16; A and B share the per-lane
// map: elem[lane l][j] = M[tile*16 + (l&15)][ks*32 + (l>>4)*8 + j]):
//   Ws: frag f = (nt*32 + ks)*64 + l     nt<16 (W col-tiles), ks<32
//   hs: frag f = (t*8  + ks)*64 + l      t<256 (h row-tiles), ks<8  (K=256)

static __device__ __forceinline__ unsigned short f2bf(float f) {
    unsigned int u = __float_as_uint(f);
    u = (u + 0x7fffu + ((u >> 16) & 1u)) >> 16;
    return (unsigned short)u;
}
static __device__ __forceinline__ unsigned int pack2(float lo, float hi) {
    return (unsigned int)f2bf(lo) | ((unsigned int)f2bf(hi) << 16);
}
// order-preserving float<->uint key (unsigned compare == float compare)
static __device__ __forceinline__ unsigned int fkey(float f) {
    unsigned int b = __float_as_uint(f);
    return (b & 0x80000000u) ? ~b : (b | 0x80000000u);
}
static __device__ __forceinline__ float funkey(unsigned int u) {
    return __uint_as_float((u & 0x80000000u) ? (u & 0x7fffffffu) : ~u);
}

// ---------------------------------------------------------------------------
// Kernel 0 (setup): Ws fragment gather + sq/out/key-slot init. 128 blocks.
// ---------------------------------------------------------------------------
__global__ __launch_bounds__(256) void setup(const float* __restrict__ W,
                                             unsigned short* __restrict__ Ws,
                                             float* __restrict__ sq,
                                             unsigned int* __restrict__ pmaxk,
                                             unsigned int* __restrict__ pmink,
                                             float* __restrict__ out) {
    const int f = blockIdx.x * 256 + threadIdx.x;    // 32768 Ws frags
    {
        const int l  = f & 63;
        const int ks = (f >> 6) & 31;
        const int nt = f >> 11;
        const int col = nt * 16 + (l & 15);
        const int k0  = ks * 32 + (l >> 4) * 8;
        float a[8];
#pragma unroll
        for (int j = 0; j < 8; ++j) a[j] = W[(size_t)(k0 + j) * DOUT + col];
        uint4 v;
        v.x = pack2(a[0], a[1]);
        v.y = pack2(a[2], a[3]);
        v.z = pack2(a[4], a[5]);
        v.w = pack2(a[6], a[7]);
        *(uint4*)&Ws[(size_t)f * 8] = v;
    }
    if (f < NROWS) {
        sq[f]    = 0.0f;
        pmaxk[f] = 0u;            // < any real key
        pmink[f] = 0xFFFFFFFFu;   // > any real key
    }
    if (f == 0) *out = 0.0f;
}

// ---------------------------------------------------------------------------
// Kernel 1: h = x@W + b with x staged ONCE per row-tile (512 thr, 256 blocks).
// Stage: 16x1024 fp32 coalesced -> bf16 frag-order LDS (528-short ks stride).
// Wave w (0..7): nt pair w*2+{0,1}: 32 ks x (1 LDS A-frag + 2 B-frags + 2
// MFMA). Epilogue: bias, row-sq atomicAdd, per-wave transpose -> hs k-slice w.
// ---------------------------------------------------------------------------
__global__ __launch_bounds__(512) void gemm1_direct(
    const float* __restrict__ x, const unsigned short* __restrict__ Ws,
    const float* __restrict__ b,
    unsigned short* __restrict__ hs, float* __restrict__ sq) {
    __shared__ __align__(16) short Axs[32 * 528];    // 33792 B frag-order A strip
    __shared__ __align__(16) short T[8][16][36];     // per-wave C transpose

    const int tid = threadIdx.x;
    const int w   = tid >> 6;            // wave 0..7
    const int l   = tid & 63;
    const int m16 = l & 15;
    const int q   = l >> 4;
    const int t   = blockIdx.x;          // x row-tile (0..255)

    // ---- stage x strip (once) ----
    const int r  = tid >> 5;             // row 0..15
    const int cc = tid & 31;
    const float* xrow = x + (size_t)(t * 16 + r) * DIN;
#pragma unroll
    for (int s = 0; s < 4; ++s) {
        const int c = s * 256 + cc * 8;
        const float4 p0 = *(const float4*)(xrow + c);
        const float4 p1 = *(const float4*)(xrow + c + 4);
        uint4 v;
        v.x = pack2(p0.x, p0.y);
        v.y = pack2(p0.z, p0.w);
        v.z = pack2(p1.x, p1.y);
        v.w = pack2(p1.z, p1.w);
        const int ks = c >> 5;
        const int lw = ((c >> 3) & 3) * 16 + r;
        *(uint4*)&Axs[ks * 528 + lw * 8] = v;
    }
    __syncthreads();

    // ---- K-loop ----
    const int nt0 = w * 2;
    const bfrag* B0 = (const bfrag*)Ws + ((size_t)nt0 * 32) * 64 + l;
    const bfrag* B1 = (const bfrag*)Ws + ((size_t)(nt0 + 1) * 32) * 64 + l;

    ffrag acc0 = {}, acc1 = {};
#pragma unroll
    for (int ks = 0; ks < 32; ++ks) {
        const bfrag a = *(const bfrag*)&Axs[ks * 528 + l * 8];
        acc0 = __builtin_amdgcn_mfma_f32_16x16x32_bf16(a, B0[ks * 64], acc0, 0, 0, 0);
        acc1 = __builtin_amdgcn_mfma_f32_16x16x32_bf16(a, B1[ks * 64], acc1, 0, 0, 0);
    }

    // ---- epilogue ----
    const float bc0 = b[nt0 * 16 + m16];
    const float bc1 = b[(nt0 + 1) * 16 + m16];
    float hv0[4], hv1[4];
#pragma unroll
    for (int reg = 0; reg < 4; ++reg) {
        hv0[reg] = acc0[reg] + bc0;
        hv1[reg] = acc1[reg] + bc1;
    }

    // row-sq partial over this wave's 32 features
#pragma unroll
    for (int reg = 0; reg < 4; ++reg) {
        float p = hv0[reg] * hv0[reg] + hv1[reg] * hv1[reg];
#pragma unroll
        for (int mask = 1; mask < 16; mask <<= 1) p += __shfl_xor(p, mask);
        if (m16 == 0) atomicAdd(&sq[t * 16 + q * 4 + reg], p);
    }

    // per-wave transpose (rows q*4+reg, cols u*16+m16) -> hs frag order
#pragma unroll
    for (int reg = 0; reg < 4; ++reg) {
        T[w][q * 4 + reg][m16]      = f2bf(hv0[reg]);
        T[w][q * 4 + reg][16 + m16] = f2bf(hv1[reg]);
    }
    // same-wave LDS RAW: in-order LDS ops + lgkmcnt wait; no barrier needed
    bfrag v = *(const bfrag*)&T[w][m16][q * 8];
    ((bfrag*)hs)[((size_t)t * 8 + w) * 64 + l] = v;   // full-wave 1KB store
}

// ---------------------------------------------------------------------------
// Kernel 2: triangular register-direct Gram; results accumulate via global
// atomic max/min on order-preserving uint keys (no partial arrays).
// ---------------------------------------------------------------------------
__global__ __launch_bounds__(256) void hardest_tri(
    const unsigned short* __restrict__ hs, const float* __restrict__ sq,
    const int* __restrict__ targets,
    unsigned int* __restrict__ pmaxk, unsigned int* __restrict__ pmink) {
    const int tid = threadIdx.x;
    const int w   = tid >> 6;
    const int wi  = w & 1, wj = w >> 1;
    const int l   = tid & 63;
    const int m16 = l & 15;
    const int q   = l >> 4;

    // decode triangular pair index k -> (bi <= bj)
    const int k = blockIdx.x;
    int bj = (int)((sqrtf(8.0f * (float)k + 1.0f) - 1.0f) * 0.5f);
    while ((bj + 1) * (bj + 2) / 2 <= k) ++bj;
    while (bj * (bj + 1) / 2 > k) --bj;
    const int bi = k - bj * (bj + 1) / 2;
    const bool diag = (bi == bj);

    const int iw = bi * 128 + wi * 64;
    const int jw = bj * 128 + wj * 64;
    const int tA = iw >> 4;
    const int tB = jw >> 4;

    ffrag acc[4][4] = {};                        // [mi][nj]

#pragma unroll
    for (int ks = 0; ks < 8; ++ks) {
        bfrag a[4], bb[4];
#pragma unroll
        for (int mi = 0; mi < 4; ++mi)
            a[mi] = *(const bfrag*)&hs[(((size_t)(tA + mi) * 8 + ks) * 64 + l) * 8];
#pragma unroll
        for (int nj = 0; nj < 4; ++nj)
            bb[nj] = *(const bfrag*)&hs[(((size_t)(tB + nj) * 8 + ks) * 64 + l) * 8];
#pragma unroll
        for (int mi = 0; mi < 4; ++mi)
#pragma unroll
            for (int nj = 0; nj < 4; ++nj)
                acc[mi][nj] = __builtin_amdgcn_mfma_f32_16x16x32_bf16(
                    a[mi], bb[nj], acc[mi][nj], 0, 0, 0);
    }

    // ---- fused epilogue, both directions ----
    int   tj[4];
    float svj[4];
#pragma unroll
    for (int nj = 0; nj < 4; ++nj) {
        const int col = jw + nj * 16 + m16;
        tj[nj]  = targets[col];
        svj[nj] = sq[col];
    }

    float cmx[4], cmn[4];
#pragma unroll
    for (int nj = 0; nj < 4; ++nj) { cmx[nj] = -INFINITY; cmn[nj] = INFINITY; }

#pragma unroll
    for (int mi = 0; mi < 4; ++mi)
#pragma unroll
        for (int reg = 0; reg < 4; ++reg) {
            const int row = iw + mi * 16 + q * 4 + reg;
            const int ti  = targets[row];
            const float si = sq[row];
            float mx = -INFINITY, mn = INFINITY;
#pragma unroll
            for (int nj = 0; nj < 4; ++nj) {
                const float g    = acc[mi][nj][reg];
                const float vrow = fmaf(-2.0f, g, svj[nj]);
                const float vcol = fmaf(-2.0f, g, si);
                if (tj[nj] == ti) {
                    mx = fmaxf(mx, vrow);
                    cmx[nj] = fmaxf(cmx[nj], vcol);
                } else {
                    mn = fminf(mn, vrow);
                    cmn[nj] = fminf(cmn[nj], vcol);
                }
            }
            // row-side: reduce over the 16 m16-lanes, then one atomic pair
#pragma unroll
            for (int mask = 1; mask < 16; mask <<= 1) {
                mx = fmaxf(mx, __shfl_xor(mx, mask));
                mn = fminf(mn, __shfl_xor(mn, mask));
            }
            if (m16 == 0) {
                atomicMax(&pmaxk[row], fkey(mx));
                atomicMin(&pmink[row], fkey(mn));
            }
        }

    // col-side: reduce over the q bits (lanes 16,32 apart), skip on diagonal
    if (!diag) {
#pragma unroll
        for (int nj = 0; nj < 4; ++nj) {
            float mx = cmx[nj], mn = cmn[nj];
            mx = fmaxf(mx, __shfl_xor(mx, 16));
            mn = fminf(mn, __shfl_xor(mn, 16));
            mx = fmaxf(mx, __shfl_xor(mx, 32));
            mn = fminf(mn, __shfl_xor(mn, 32));
            if (q == 0) {
                const int col = jw + nj * 16 + m16;
                atomicMax(&pmaxk[col], fkey(mx));
                atomicMin(&pmink[col], fkey(mn));
            }
        }
    }
}

// ---------------------------------------------------------------------------
// Kernel 3: decode keys, per-row loss, sum -> out[0]. 16 blocks.
// ---------------------------------------------------------------------------
__global__ __launch_bounds__(256) void finalize(const float* __restrict__ sq,
                                                const unsigned int* __restrict__ pmaxk,
                                                const unsigned int* __restrict__ pmink,
                                                float* __restrict__ out) {
    __shared__ float wsum[4];
    const int i = blockIdx.x * 256 + threadIdx.x;
    const float mp = funkey(pmaxk[i]);
    const float mn = funkey(pmink[i]);
    const float si = sq[i];
    const float hp = sqrtf(fmaxf(si + mp, 0.0f));
    const float hn = sqrtf(fmaxf(si + mn, 0.0f));
    const float d  = hp - hn;
    float li = fmaxf(d, 0.0f) + log1pf(expf(-fabsf(d)));  // stable log1p(exp(d))
#pragma unroll
    for (int off = 32; off; off >>= 1) li += __shfl_down(li, off);
    const int lane = threadIdx.x & 63, wv = threadIdx.x >> 6;
    if (lane == 0) wsum[wv] = li;
    __syncthreads();
    if (threadIdx.x == 0)
        atomicAdd(out, wsum[0] + wsum[1] + wsum[2] + wsum[3]);
}

// ---------------------------------------------------------------------------
extern "C" void kernel_launch(void* const* d_in, const int* in_sizes, int n_in,
                              void* d_out, int out_size, void* d_ws, size_t ws_size,
                              hipStream_t stream) {
    const float* x       = (const float*)d_in[0];
    const float* W       = (const float*)d_in[1];
    const float* b       = (const float*)d_in[2];
    const int*   targets = (const int*)d_in[3];
    float* out = (float*)d_out;

    unsigned short* Ws    = (unsigned short*)d_ws;              // 256*1024 bf16 (frag order)
    unsigned short* hs    = Ws + DOUT * DIN;                    // 4096*256 bf16 (frag order)
    float*          sq    = (float*)(hs + NROWS * DOUT);        // 4096
    unsigned int*   pmaxk = (unsigned int*)(sq + NROWS);        // 4096 keys
    unsigned int*   pmink = pmaxk + NROWS;                      // 4096 keys

    setup<<<16 * 32 * 64 / 256, 256, 0, stream>>>(W, Ws, sq, pmaxk, pmink, out);
    gemm1_direct<<<NROWS / 16, 512, 0, stream>>>(x, Ws, b, hs, sq);
    hardest_tri<<<NPAIR, 256, 0, stream>>>(hs, sq, targets, pmaxk, pmink);
    finalize<<<NROWS / 256, 256, 0, stream>>>(sq, pmaxk, pmink, out);
}

// Round 15
// 97.748 us; speedup vs baseline: 1.3057x; 1.0131x over previous
//
#include <hip/hip_runtime.h>
#include <math.h>

#define NROWS 4096
#define DIN   1024
#define DOUT  256
#define NPAIR 528        // 32*33/2 triangular 128x128 block pairs

using bfrag = __attribute__((ext_vector_type(8))) short;  // 8 bf16 (4 VGPRs)
using ffrag = __attribute__((ext_vector_type(4))) float;  // 4 fp32 acc

// Fragment-order layouts (mfma_f32_16x16x32_bf16; A and B share the per-lane
// map: elem[lane l][j] = M[tile*16 + (l&15)][ks*32 + (l>>4)*8 + j]):
//   Ws: frag f = (nt*32 + ks)*64 + l     nt<16 (W col-tiles), ks<32
//   hs: frag f = (t*8  + ks)*64 + l      t<256 (h row-tiles), ks<8  (K=256)

static __device__ __forceinline__ unsigned short f2bf(float f) {
    unsigned int u = __float_as_uint(f);
    u = (u + 0x7fffu + ((u >> 16) & 1u)) >> 16;
    return (unsigned short)u;
}
static __device__ __forceinline__ unsigned int pack2(float lo, float hi) {
    return (unsigned int)f2bf(lo) | ((unsigned int)f2bf(hi) << 16);
}
// order-preserving float<->uint key (unsigned compare == float compare)
static __device__ __forceinline__ unsigned int fkey(float f) {
    unsigned int b = __float_as_uint(f);
    return (b & 0x80000000u) ? ~b : (b | 0x80000000u);
}
static __device__ __forceinline__ float funkey(unsigned int u) {
    return __uint_as_float((u & 0x80000000u) ? (u & 0x7fffffffu) : ~u);
}

// ---------------------------------------------------------------------------
// Kernel 0 (setup): Ws fragment gather + sq/out/key-slot init. 128 blocks.
// ---------------------------------------------------------------------------
__global__ __launch_bounds__(256) void setup(const float* __restrict__ W,
                                             unsigned short* __restrict__ Ws,
                                             float* __restrict__ sq,
                                             unsigned int* __restrict__ pmaxk,
                                             unsigned int* __restrict__ pmink,
                                             float* __restrict__ out) {
    const int f = blockIdx.x * 256 + threadIdx.x;    // 32768 Ws frags
    {
        const int l  = f & 63;
        const int ks = (f >> 6) & 31;
        const int nt = f >> 11;
        const int col = nt * 16 + (l & 15);
        const int k0  = ks * 32 + (l >> 4) * 8;
        float a[8];
#pragma unroll
        for (int j = 0; j < 8; ++j) a[j] = W[(size_t)(k0 + j) * DOUT + col];
        uint4 v;
        v.x = pack2(a[0], a[1]);
        v.y = pack2(a[2], a[3]);
        v.z = pack2(a[4], a[5]);
        v.w = pack2(a[6], a[7]);
        *(uint4*)&Ws[(size_t)f * 8] = v;
    }
    if (f < NROWS) {
        sq[f]    = 0.0f;
        pmaxk[f] = 0u;            // < any real key
        pmink[f] = 0xFFFFFFFFu;   // > any real key
    }
    if (f == 0) *out = 0.0f;
}

// ---------------------------------------------------------------------------
// Kernel 1: h = x@W + b. 256 blocks x 1024 threads (16 waves = 16 nt tiles),
// 2 blocks/CU -> 32 waves/CU for latency hiding after the ws poison sweep.
// Stage: 16x1024 fp32 coalesced (each wave one 2KB row run) -> bf16
// frag-order LDS. Wave w: nt = w: 32 ks x (1 LDS A-frag + 1 Ws frag + MFMA).
// Epilogue: bias, row-sq atomicAdd, cross-wave T transpose -> hs (barrier).
// ---------------------------------------------------------------------------
__global__ __launch_bounds__(1024) void gemm1_direct(
    const float* __restrict__ x, const unsigned short* __restrict__ Ws,
    const float* __restrict__ b,
    unsigned short* __restrict__ hs, float* __restrict__ sq) {
    __shared__ __align__(16) short Axs[32 * 528];    // 33792 B frag-order A strip
    __shared__ __align__(16) short T[16][16][36];    // 18432 B C transpose

    const int tid = threadIdx.x;
    const int w   = tid >> 6;            // wave 0..15 = nt tile
    const int l   = tid & 63;
    const int m16 = l & 15;
    const int q   = l >> 4;
    const int t   = blockIdx.x;          // x row-tile (0..255)

    // ---- stage x strip (wave w loads row w, fully coalesced) ----
    const float* xrow = x + (size_t)(t * 16 + w) * DIN;
#pragma unroll
    for (int s = 0; s < 2; ++s) {
        const int c = s * 512 + l * 8;
        const float4 p0 = *(const float4*)(xrow + c);
        const float4 p1 = *(const float4*)(xrow + c + 4);
        uint4 v;
        v.x = pack2(p0.x, p0.y);
        v.y = pack2(p0.z, p0.w);
        v.z = pack2(p1.x, p1.y);
        v.w = pack2(p1.z, p1.w);
        const int ks = c >> 5;
        const int lw = ((c >> 3) & 3) * 16 + w;
        *(uint4*)&Axs[ks * 528 + lw * 8] = v;
    }
    __syncthreads();

    // ---- K-loop: one nt tile per wave ----
    const bfrag* B = (const bfrag*)Ws + ((size_t)w * 32) * 64 + l;
    ffrag acc = {};
#pragma unroll
    for (int ks = 0; ks < 32; ++ks) {
        const bfrag a = *(const bfrag*)&Axs[ks * 528 + l * 8];
        acc = __builtin_amdgcn_mfma_f32_16x16x32_bf16(a, B[ks * 64], acc, 0, 0, 0);
    }

    // ---- epilogue ----
    const float bc = b[w * 16 + m16];
    float hv[4];
#pragma unroll
    for (int reg = 0; reg < 4; ++reg) hv[reg] = acc[reg] + bc;

    // row-sq partial over this wave's 16 features
#pragma unroll
    for (int reg = 0; reg < 4; ++reg) {
        float p = hv[reg] * hv[reg];
#pragma unroll
        for (int mask = 1; mask < 16; mask <<= 1) p += __shfl_xor(p, mask);
        if (m16 == 0) atomicAdd(&sq[t * 16 + q * 4 + reg], p);
    }

    // T[w][row][col16] = h[t*16+row][w*16+col16]
#pragma unroll
    for (int reg = 0; reg < 4; ++reg)
        T[w][q * 4 + reg][m16] = f2bf(hv[reg]);
    __syncthreads();

    // emit hs frags: feature ks*32 + q*8 + j = T[2ks + (q>>1)][m16][(q&1)*8+j]
    if (tid < 512) {
        const int ks = tid >> 6;
        const int ll = tid & 63;
        const int qq = ll >> 4;
        bfrag v = *(const bfrag*)&T[2 * ks + (qq >> 1)][ll & 15][(qq & 1) * 8];
        ((bfrag*)hs)[((size_t)t * 8 + ks) * 64 + ll] = v;   // 1KB/wave store
    }
}

// ---------------------------------------------------------------------------
// Kernel 2: triangular register-direct Gram; results accumulate via global
// atomic max/min on order-preserving uint keys (no partial arrays).
// ---------------------------------------------------------------------------
__global__ __launch_bounds__(256) void hardest_tri(
    const unsigned short* __restrict__ hs, const float* __restrict__ sq,
    const int* __restrict__ targets,
    unsigned int* __restrict__ pmaxk, unsigned int* __restrict__ pmink) {
    const int tid = threadIdx.x;
    const int w   = tid >> 6;
    const int wi  = w & 1, wj = w >> 1;
    const int l   = tid & 63;
    const int m16 = l & 15;
    const int q   = l >> 4;

    // decode triangular pair index k -> (bi <= bj)
    const int k = blockIdx.x;
    int bj = (int)((sqrtf(8.0f * (float)k + 1.0f) - 1.0f) * 0.5f);
    while ((bj + 1) * (bj + 2) / 2 <= k) ++bj;
    while (bj * (bj + 1) / 2 > k) --bj;
    const int bi = k - bj * (bj + 1) / 2;
    const bool diag = (bi == bj);

    const int iw = bi * 128 + wi * 64;
    const int jw = bj * 128 + wj * 64;
    const int tA = iw >> 4;
    const int tB = jw >> 4;

    ffrag acc[4][4] = {};                        // [mi][nj]

#pragma unroll
    for (int ks = 0; ks < 8; ++ks) {
        bfrag a[4], bb[4];
#pragma unroll
        for (int mi = 0; mi < 4; ++mi)
            a[mi] = *(const bfrag*)&hs[(((size_t)(tA + mi) * 8 + ks) * 64 + l) * 8];
#pragma unroll
        for (int nj = 0; nj < 4; ++nj)
            bb[nj] = *(const bfrag*)&hs[(((size_t)(tB + nj) * 8 + ks) * 64 + l) * 8];
#pragma unroll
        for (int mi = 0; mi < 4; ++mi)
#pragma unroll
            for (int nj = 0; nj < 4; ++nj)
                acc[mi][nj] = __builtin_amdgcn_mfma_f32_16x16x32_bf16(
                    a[mi], bb[nj], acc[mi][nj], 0, 0, 0);
    }

    // ---- fused epilogue, both directions ----
    int   tj[4];
    float svj[4];
#pragma unroll
    for (int nj = 0; nj < 4; ++nj) {
        const int col = jw + nj * 16 + m16;
        tj[nj]  = targets[col];
        svj[nj] = sq[col];
    }

    float cmx[4], cmn[4];
#pragma unroll
    for (int nj = 0; nj < 4; ++nj) { cmx[nj] = -INFINITY; cmn[nj] = INFINITY; }

#pragma unroll
    for (int mi = 0; mi < 4; ++mi)
#pragma unroll
        for (int reg = 0; reg < 4; ++reg) {
            const int row = iw + mi * 16 + q * 4 + reg;
            const int ti  = targets[row];
            const float si = sq[row];
            float mx = -INFINITY, mn = INFINITY;
#pragma unroll
            for (int nj = 0; nj < 4; ++nj) {
                const float g    = acc[mi][nj][reg];
                const float vrow = fmaf(-2.0f, g, svj[nj]);
                const float vcol = fmaf(-2.0f, g, si);
                if (tj[nj] == ti) {
                    mx = fmaxf(mx, vrow);
                    cmx[nj] = fmaxf(cmx[nj], vcol);
                } else {
                    mn = fminf(mn, vrow);
                    cmn[nj] = fminf(cmn[nj], vcol);
                }
            }
            // row-side: reduce over the 16 m16-lanes, then one atomic pair
#pragma unroll
            for (int mask = 1; mask < 16; mask <<= 1) {
                mx = fmaxf(mx, __shfl_xor(mx, mask));
                mn = fminf(mn, __shfl_xor(mn, mask));
            }
            if (m16 == 0) {
                atomicMax(&pmaxk[row], fkey(mx));
                atomicMin(&pmink[row], fkey(mn));
            }
        }

    // col-side: reduce over the q bits (lanes 16,32 apart), skip on diagonal
    if (!diag) {
#pragma unroll
        for (int nj = 0; nj < 4; ++nj) {
            float mx = cmx[nj], mn = cmn[nj];
            mx = fmaxf(mx, __shfl_xor(mx, 16));
            mn = fminf(mn, __shfl_xor(mn, 16));
            mx = fmaxf(mx, __shfl_xor(mx, 32));
            mn = fminf(mn, __shfl_xor(mn, 32));
            if (q == 0) {
                const int col = jw + nj * 16 + m16;
                atomicMax(&pmaxk[col], fkey(mx));
                atomicMin(&pmink[col], fkey(mn));
            }
        }
    }
}

// ---------------------------------------------------------------------------
// Kernel 3: decode keys, per-row loss, sum -> out[0]. 16 blocks.
// ---------------------------------------------------------------------------
__global__ __launch_bounds__(256) void finalize(const float* __restrict__ sq,
                                                const unsigned int* __restrict__ pmaxk,
                                                const unsigned int* __restrict__ pmink,
                                                float* __restrict__ out) {
    __shared__ float wsum[4];
    const int i = blockIdx.x * 256 + threadIdx.x;
    const float mp = funkey(pmaxk[i]);
    const float mn = funkey(pmink[i]);
    const float si = sq[i];
    const float hp = sqrtf(fmaxf(si + mp, 0.0f));
    const float hn = sqrtf(fmaxf(si + mn, 0.0f));
    const float d  = hp - hn;
    float li = fmaxf(d, 0.0f) + log1pf(expf(-fabsf(d)));  // stable log1p(exp(d))
#pragma unroll
    for (int off = 32; off; off >>= 1) li += __shfl_down(li, off);
    const int lane = threadIdx.x & 63, wv = threadIdx.x >> 6;
    if (lane == 0) wsum[wv] = li;
    __syncthreads();
    if (threadIdx.x == 0)
        atomicAdd(out, wsum[0] + wsum[1] + wsum[2] + wsum[3]);
}

// ---------------------------------------------------------------------------
extern "C" void kernel_launch(void* const* d_in, const int* in_sizes, int n_in,
                              void* d_out, int out_size, void* d_ws, size_t ws_size,
                              hipStream_t stream) {
    const float* x       = (const float*)d_in[0];
    const float* W       = (const float*)d_in[1];
    const float* b       = (const float*)d_in[2];
    const int*   targets = (const int*)d_in[3];
    float* out = (float*)d_out;

    unsigned short* Ws    = (unsigned short*)d_ws;              // 256*1024 bf16 (frag order)
    unsigned short* hs    = Ws + DOUT * DIN;                    // 4096*256 bf16 (frag order)
    float*          sq    = (float*)(hs + NROWS * DOUT);        // 4096
    unsigned int*   pmaxk = (unsigned int*)(sq + NROWS);        // 4096 keys
    unsigned int*   pmink = pmaxk + NROWS;                      // 4096 keys

    setup<<<16 * 32 * 64 / 256, 256, 0, stream>>>(W, Ws, sq, pmaxk, pmink, out);
    gemm1_direct<<<NROWS / 16, 1024, 0, stream>>>(x, Ws, b, hs, sq);
    hardest_tri<<<NPAIR, 256, 0, stream>>>(hs, sq, targets, pmaxk, pmink);
    finalize<<<NROWS / 256, 256, 0, stream>>>(sq, pmaxk, pmink, out);
}